// Round 1
// 81.051 us; speedup vs baseline: 1.0124x; 1.0124x over previous
//
#include <hip/hip_runtime.h>

// Chamfer loss, B=8, N=M=4096, D=3, fp32 — single fused kernel.
//
// Grid = (own-tile, dir, batch) = (32, 2, 8) = 512 blocks, 256 threads.
// Block threads = 8 own-slots x 32 oth-splits:
//   - own: 128 points/block; each thread owns 16 (8 packed pairs).
//   - oth: all 4096 points staged through LDS in 2 chunks of 2048
//     (float4 = x,y,z,|q|^2; padded +1 float4 per 64 so the 8 split-groups
//     of a wave read disjoint bank quads -> conflict-free ds_read_b128).
// Inner loop is the proven Gram-form pk_fma path: g = |q|^2 - 2 p.q with
// q broadcast via op_sel, 2-j v_min3 folding (2 VALU instr-lanes / pair).
// Epilogue: +|p|^2, min across the 32 splits (shfl_xor 8/16/32 + LDS across
// the 4 waves), clamp, sqrt, block sum, one atomicAdd. No workspace, no
// second kernel, no 16 MB partials round-trip.

constexpr int B = 8;
constexpr int N = 4096;

#define TPB 256
#define OWN 128            // own points per block
#define RP 8               // packed own pairs per thread (16 own points)
#define NSP 32             // oth splits (tid >> 3)
#define CH 2048            // oth points per LDS chunk
#define SPLEN (CH / NSP)   // 64 oth per split per chunk

typedef float float2v __attribute__((ext_vector_type(2)));

__global__ __launch_bounds__(TPB, 2) void chamfer_fused(
        const float* __restrict__ x1, const float* __restrict__ y1,
        float* __restrict__ out, float scale) {
    __shared__ float4 qs[CH + CH / 64];   // 2080 float4 = 33 KB (padded)
    __shared__ float red[4 * OWN];        // per-wave partial minima
    __shared__ float wsum[4];

    const int tid  = threadIdx.x;
    const int tile = blockIdx.x;
    const int dir  = blockIdx.y;
    const int b    = blockIdx.z;

    const float* own = (dir ? y1 : x1) + (size_t)b * N * 3;
    const float* oth = (dir ? x1 : y1) + (size_t)b * N * 3;
    const float2* o2 = (const float2*)oth;

    const int slot = tid & 7;     // own-slot (16 own points)
    const int sp   = tid >> 3;    // oth-split [0,32)

    // ---- own-point coefficients: 8 packed pairs (mx,my,mz = -2*coord).
    float2v mx2[RP], my2[RP], mz2[RP], xx2[RP], acc2[RP];
    {
        const float2* p2 = (const float2*)(own + (size_t)(tile * OWN + slot * 16) * 3);
        #pragma unroll
        for (int p = 0; p < RP; p++) {
            float2 a = p2[3 * p], d = p2[3 * p + 1], e = p2[3 * p + 2];
            // point0 = (a.x, a.y, d.x); point1 = (d.y, e.x, e.y)
            mx2[p] = float2v{-2.0f * a.x, -2.0f * d.y};
            my2[p] = float2v{-2.0f * a.y, -2.0f * e.x};
            mz2[p] = float2v{-2.0f * d.x, -2.0f * e.y};
            xx2[p] = float2v{fmaf(a.x, a.x, fmaf(a.y, a.y, d.x * d.x)),
                             fmaf(d.y, d.y, fmaf(e.x, e.x, e.y * e.y))};
            acc2[p] = float2v{3.4e38f, 3.4e38f};
        }
    }

    for (int c = 0; c < 2; c++) {
        if (c) __syncthreads();           // qs reuse guard
        // ---- stage 2048 oth points (1024 pairs, 4 per thread), coalesced
        //      float2 reads, padded float4 LDS writes.
        #pragma unroll
        for (int k = 0; k < 4; k++) {
            int u = tid + k * TPB;        // pair index within chunk [0,1024)
            float2 a = o2[c * 3072 + 3 * u];
            float2 d = o2[c * 3072 + 3 * u + 1];
            float2 e = o2[c * 3072 + 3 * u + 2];
            int i0 = 2 * u, i1 = 2 * u + 1;
            qs[i0 + (i0 >> 6)] = make_float4(a.x, a.y, d.x,
                    fmaf(a.x, a.x, fmaf(a.y, a.y, d.x * d.x)));
            qs[i1 + (i1 >> 6)] = make_float4(d.y, e.x, e.y,
                    fmaf(d.y, d.y, fmaf(e.x, e.x, e.y * e.y)));
        }
        __syncthreads();

        // ---- min over this thread's 64-oth slice of the chunk.
        const float4* q = qs + sp * (SPLEN + 1);   // 65 float4 stride (pad)
        #pragma unroll 4
        for (int j = 0; j < SPLEN; j += 2) {
            union { float4 f4; float2v f2[2]; } qa0, qa1;
            qa0.f4 = q[j];                // ds_read_b128, 8-group broadcast
            qa1.f4 = q[j + 1];
            float2v xy0 = qa0.f2[0], zw0 = qa0.f2[1];
            float2v xy1 = qa1.f2[0], zw1 = qa1.f2[1];
            #pragma unroll
            for (int p = 0; p < RP; p++) {
                float2v g0, g1;
                // g = q.z * mz + q.w   (q.z, q.w broadcast to both halves)
                asm("v_pk_fma_f32 %0, %1, %2, %1 op_sel:[0,0,1] op_sel_hi:[0,1,1]"
                    : "=v"(g0) : "v"(zw0), "v"(mz2[p]));
                asm("v_pk_fma_f32 %0, %1, %2, %1 op_sel:[0,0,1] op_sel_hi:[0,1,1]"
                    : "=v"(g1) : "v"(zw1), "v"(mz2[p]));
                // g = q.y * my + g
                asm("v_pk_fma_f32 %0, %1, %2, %3 op_sel:[1,0,0] op_sel_hi:[1,1,1]"
                    : "=v"(g0) : "v"(xy0), "v"(my2[p]), "v"(g0));
                asm("v_pk_fma_f32 %0, %1, %2, %3 op_sel:[1,0,0] op_sel_hi:[1,1,1]"
                    : "=v"(g1) : "v"(xy1), "v"(my2[p]), "v"(g1));
                // g = q.x * mx + g
                asm("v_pk_fma_f32 %0, %1, %2, %3 op_sel:[0,0,0] op_sel_hi:[0,1,1]"
                    : "=v"(g0) : "v"(xy0), "v"(mx2[p]), "v"(g0));
                asm("v_pk_fma_f32 %0, %1, %2, %3 op_sel:[0,0,0] op_sel_hi:[0,1,1]"
                    : "=v"(g1) : "v"(xy1), "v"(mx2[p]), "v"(g1));
                // 2-j fold -> v_min3_f32 per half
                acc2[p].x = fminf(fminf(acc2[p].x, g0.x), g1.x);
                acc2[p].y = fminf(fminf(acc2[p].y, g0.y), g1.y);
            }
        }
    }

    // ---- +|p|^2, then min across the 32 oth-splits.
    #pragma unroll
    for (int p = 0; p < RP; p++) acc2[p] += xx2[p];   // v_pk_add_f32

    const int lane = tid & 63;
    const int wid  = tid >> 6;
    // in-wave: splits live on lane bits 3..5 -> butterfly 8/16/32
    #pragma unroll
    for (int p = 0; p < RP; p++) {
        #pragma unroll
        for (int e = 0; e < 2; e++) {
            float v = acc2[p][e];
            v = fminf(v, __shfl_xor(v, 8, 64));
            v = fminf(v, __shfl_xor(v, 16, 64));
            v = fminf(v, __shfl_xor(v, 32, 64));
            acc2[p][e] = v;
        }
    }
    if (lane < 8) {   // lane == slot: one writer per (wave, own point)
        #pragma unroll
        for (int p = 0; p < RP; p++) {
            red[wid * OWN + lane * 16 + 2 * p]     = acc2[p].x;
            red[wid * OWN + lane * 16 + 2 * p + 1] = acc2[p].y;
        }
    }
    __syncthreads();

    // ---- finish: cross-wave min, clamp, sqrt, block sum, one atomic.
    float s = 0.0f;
    if (tid < OWN) {
        float m = fminf(fminf(red[tid], red[OWN + tid]),
                        fminf(red[2 * OWN + tid], red[3 * OWN + tid]));
        s = sqrtf(1e-8f + fmaxf(m, 0.0f));
    }
    #pragma unroll
    for (int off = 32; off > 0; off >>= 1) s += __shfl_down(s, off, 64);
    if (lane == 0) wsum[wid] = s;
    __syncthreads();
    if (tid == 0)
        atomicAdd(out, (wsum[0] + wsum[1] + wsum[2] + wsum[3]) * scale);
}

extern "C" void kernel_launch(void* const* d_in, const int* in_sizes, int n_in,
                              void* d_out, int out_size, void* d_ws, size_t ws_size,
                              hipStream_t stream) {
    (void)in_sizes; (void)n_in; (void)d_ws; (void)ws_size; (void)out_size;
    const float* x1 = (const float*)d_in[0];   // (B, N, 3)
    const float* y1 = (const float*)d_in[1];   // (B, M, 3)

    hipMemsetAsync(d_out, 0, sizeof(float), stream);   // d_out is poisoned

    dim3 grid(N / OWN, 2, B);                  // 32 x 2 x 8 = 512 blocks
    chamfer_fused<<<grid, TPB, 0, stream>>>(x1, y1, (float*)d_out,
                                            1.0f / (B * N));
}